// Round 1
// baseline (3972.702 us; speedup 1.0000x reference)
//
#include <hip/hip_runtime.h>

constexpr int N = 50000;
constexpr int E = 1200000;
constexpr int G = 512;
constexpr int TILES = E / 64;        // 18750 exactly
constexpr float LOG2_ = 0.69314718055994531f;

__device__ __forceinline__ float sspf(float x) {
    // shifted softplus, stable: max(x,0) + log(1+exp(-|x|)) - log(2)
    return fmaxf(x, 0.f) + __logf(1.f + __expf(-fabsf(x))) - LOG2_;
}
__device__ __forceinline__ void uadd(float* p, float v) { unsafeAtomicAdd(p, v); }

// ---------------- pre FC: out = relu(x @ pre_W^T + pre_b) ----------------
__global__ __launch_bounds__(256) void k_pre(const float* __restrict__ x,
                                             const float* __restrict__ W,
                                             const float* __restrict__ b,
                                             float* __restrict__ out) {
    __shared__ float WT[92 * 64];
    __shared__ float xs[4 * 92];
    __shared__ float bs[64];
    for (int i = threadIdx.x; i < 92 * 64; i += 256) {
        int f = i / 92, k = i - f * 92;
        WT[k * 64 + f] = W[i];
    }
    if (threadIdx.x < 64) bs[threadIdx.x] = b[threadIdx.x];
    __syncthreads();
    int f = threadIdx.x & 63, nl = threadIdx.x >> 6;
    for (int g0 = blockIdx.x; g0 < N / 4; g0 += gridDim.x) {
        int n0 = g0 * 4;
        for (int i = threadIdx.x; i < 4 * 92; i += 256) xs[i] = x[(size_t)n0 * 92 + i];
        __syncthreads();
        float acc = bs[f];
        #pragma unroll 4
        for (int k = 0; k < 92; k++) acc = fmaf(xs[nl * 92 + k], WT[k * 64 + f], acc);
        out[(size_t)(n0 + nl) * 64 + f] = fmaxf(acc, 0.f);
        __syncthreads();
    }
}

// ---------------- h = out @ cf_W1^T (no bias) ----------------
__global__ __launch_bounds__(256) void k_h(const float* __restrict__ out,
                                           const float* __restrict__ W,
                                           float* __restrict__ h) {
    __shared__ float WT[64 * 64];
    __shared__ float xs[4 * 64];
    for (int i = threadIdx.x; i < 4096; i += 256) {
        int f = i >> 6, j = i & 63;
        WT[j * 64 + f] = W[i];
    }
    __syncthreads();
    int f = threadIdx.x & 63, nl = threadIdx.x >> 6;
    for (int g0 = blockIdx.x; g0 < N / 4; g0 += gridDim.x) {
        int n0 = g0 * 4;
        if (threadIdx.x < 64)
            ((float4*)xs)[threadIdx.x] = ((const float4*)(out + (size_t)n0 * 64))[threadIdx.x];
        __syncthreads();
        float acc = 0.f;
        #pragma unroll 4
        for (int j = 0; j < 64; j++) acc = fmaf(xs[nl * 64 + j], WT[j * 64 + f], acc);
        h[(size_t)(n0 + nl) * 64 + f] = acc;
        __syncthreads();
    }
}

// ---------------- fused edge kernel ----------------
// per 64-edge tile: t = ssp(ea @ W1^T + b1); Wf = t @ W2^T + b2; Wf *= C(ew);
// msg = h[src] * Wf; atomic agg[dst] += msg
__global__ __launch_bounds__(256) void k_edge(const float* __restrict__ ea,
                                              const float* __restrict__ ew,
                                              const int* __restrict__ eidx,
                                              const float* __restrict__ h,
                                              float* __restrict__ agg,
                                              const float* __restrict__ W1,
                                              const float* __restrict__ b1,
                                              const float* __restrict__ W2,
                                              const float* __restrict__ b2) {
    __shared__ float w1T[50 * 64];   // [k][f]
    __shared__ float w2T[64 * 64];   // [j][f]
    __shared__ float buf[64 * 64];   // eaT [k][e], then tT [j][e]
    __shared__ float b1s[64], b2s[64], c_s[64];
    __shared__ int src_s[64], dst_s[64];
    int t = threadIdx.x;
    for (int i = t; i < 3200; i += 256) { int f = i / 50, k = i - f * 50; w1T[k * 64 + f] = W1[i]; }
    for (int i = t; i < 4096; i += 256) { int f = i >> 6, j = i & 63; w2T[j * 64 + f] = W2[i]; }
    if (t < 64) { b1s[t] = b1[t]; b2s[t] = b2[t]; }
    __syncthreads();

    const int e4 = (t & 15) * 4;
    const int f4 = (t >> 4) * 4;
    const int fe = t & 63, kq = t >> 6;   // for the transpose load

    for (int tile = blockIdx.x; tile < TILES; tile += gridDim.x) {
        const int e0 = tile * 64;
        // --- load edge_attr tile transposed into buf[k][e] ---
        {
            const float2* ea2 = (const float2*)ea + (size_t)e0 * 25;
            #pragma unroll
            for (int j = 0; j < 24; j += 4) {
                int kp = j + kq;
                float2 v = ea2[fe * 25 + kp];
                buf[(2 * kp) * 64 + fe] = v.x;
                buf[(2 * kp + 1) * 64 + fe] = v.y;
            }
            if (kq == 0) {
                float2 v = ea2[fe * 25 + 24];
                buf[48 * 64 + fe] = v.x;
                buf[49 * 64 + fe] = v.y;
            }
            if (t < 64) {
                float w = ew[e0 + t];
                c_s[t] = 0.5f * (__cosf(w * 0.39269908169872414f) + 1.0f);
                src_s[t] = eidx[e0 + t];
                dst_s[t] = eidx[E + e0 + t];
            }
        }
        __syncthreads();
        // --- GEMM1: a[e][f] = ssp(eaT @ W1 + b1) ---
        float a[4][4];
        #pragma unroll
        for (int i = 0; i < 4; i++)
            #pragma unroll
            for (int j = 0; j < 4; j++) a[i][j] = b1s[f4 + j];
        #pragma unroll 2
        for (int k = 0; k < 50; k++) {
            float4 av = *(const float4*)&buf[k * 64 + e4];
            float4 wv = *(const float4*)&w1T[k * 64 + f4];
            float avv[4] = {av.x, av.y, av.z, av.w};
            float wvv[4] = {wv.x, wv.y, wv.z, wv.w};
            #pragma unroll
            for (int i = 0; i < 4; i++)
                #pragma unroll
                for (int j = 0; j < 4; j++) a[i][j] = fmaf(avv[i], wvv[j], a[i][j]);
        }
        #pragma unroll
        for (int i = 0; i < 4; i++)
            #pragma unroll
            for (int j = 0; j < 4; j++) a[i][j] = sspf(a[i][j]);
        __syncthreads();   // all eaT reads done
        // --- store tT[j][e] ---
        #pragma unroll
        for (int j = 0; j < 4; j++)
            *(float4*)&buf[(f4 + j) * 64 + e4] = make_float4(a[0][j], a[1][j], a[2][j], a[3][j]);
        __syncthreads();
        // --- GEMM2: w[e][f] = tT @ W2 + b2 ---
        float w[4][4];
        #pragma unroll
        for (int i = 0; i < 4; i++)
            #pragma unroll
            for (int j = 0; j < 4; j++) w[i][j] = b2s[f4 + j];
        #pragma unroll 2
        for (int k = 0; k < 64; k++) {
            float4 tv = *(const float4*)&buf[k * 64 + e4];
            float4 wv = *(const float4*)&w2T[k * 64 + f4];
            float tvv[4] = {tv.x, tv.y, tv.z, tv.w};
            float wvv[4] = {wv.x, wv.y, wv.z, wv.w};
            #pragma unroll
            for (int i = 0; i < 4; i++)
                #pragma unroll
                for (int j = 0; j < 4; j++) w[i][j] = fmaf(tvv[i], wvv[j], w[i][j]);
        }
        // --- modulate + gather + scatter ---
        #pragma unroll
        for (int i = 0; i < 4; i++) {
            int eg = e4 + i;
            float Cv = c_s[eg];
            int sv = src_s[eg], dv = dst_s[eg];
            float4 hv = *(const float4*)&h[(size_t)sv * 64 + f4];
            float* ap = agg + (size_t)dv * 64 + f4;
            uadd(ap + 0, hv.x * w[i][0] * Cv);
            uadd(ap + 1, hv.y * w[i][1] * Cv);
            uadd(ap + 2, hv.z * w[i][2] * Cv);
            uadd(ap + 3, hv.w * w[i][3] * Cv);
        }
        __syncthreads();   // before next tile overwrites buf / c_s / src_s
    }
}

// ---------------- interaction tail + residual + BN stats ----------------
// out += ssp(agg @ cf_W2^T + cf_b2) @ int_W^T + int_b ; accumulate sum/sumsq per feature
__global__ __launch_bounds__(256) void k_post(const float* __restrict__ agg,
                                              const float* __restrict__ W2c,
                                              const float* __restrict__ b2c,
                                              const float* __restrict__ Wi,
                                              const float* __restrict__ bi,
                                              float* __restrict__ out,
                                              float* __restrict__ bnacc) {
    __shared__ float w2T[64 * 64];
    __shared__ float wiT[64 * 64];
    __shared__ float aL[16 * 64];
    __shared__ float sL[16 * 64];
    __shared__ float b2s[64], bis[64];
    int t = threadIdx.x;
    for (int i = t; i < 4096; i += 256) {
        int f = i >> 6, j = i & 63;
        w2T[j * 64 + f] = W2c[i];
        wiT[j * 64 + f] = Wi[i];
    }
    if (t < 64) { b2s[t] = b2c[t]; bis[t] = bi[t]; }
    __syncthreads();
    const int nl = t >> 4;
    const int f4 = (t & 15) * 4;
    for (int g0 = blockIdx.x; g0 < N / 16; g0 += gridDim.x) {
        int n0 = g0 * 16;
        ((float4*)aL)[t] = ((const float4*)(agg + (size_t)n0 * 64))[t];
        __syncthreads();
        float s[4] = {b2s[f4], b2s[f4 + 1], b2s[f4 + 2], b2s[f4 + 3]};
        #pragma unroll 4
        for (int j = 0; j < 64; j++) {
            float av = aL[nl * 64 + j];
            float4 wv = *(const float4*)&w2T[j * 64 + f4];
            s[0] = fmaf(av, wv.x, s[0]);
            s[1] = fmaf(av, wv.y, s[1]);
            s[2] = fmaf(av, wv.z, s[2]);
            s[3] = fmaf(av, wv.w, s[3]);
        }
        #pragma unroll
        for (int j = 0; j < 4; j++) s[j] = sspf(s[j]);
        *(float4*)&sL[nl * 64 + f4] = make_float4(s[0], s[1], s[2], s[3]);
        __syncthreads();
        float h2[4] = {bis[f4], bis[f4 + 1], bis[f4 + 2], bis[f4 + 3]};
        #pragma unroll 4
        for (int j = 0; j < 64; j++) {
            float sv = sL[nl * 64 + j];
            float4 wv = *(const float4*)&wiT[j * 64 + f4];
            h2[0] = fmaf(sv, wv.x, h2[0]);
            h2[1] = fmaf(sv, wv.y, h2[1]);
            h2[2] = fmaf(sv, wv.z, h2[2]);
            h2[3] = fmaf(sv, wv.w, h2[3]);
        }
        float4 ov = *(const float4*)&out[(size_t)(n0 + nl) * 64 + f4];
        ov.x += h2[0]; ov.y += h2[1]; ov.z += h2[2]; ov.w += h2[3];
        *(float4*)&out[(size_t)(n0 + nl) * 64 + f4] = ov;
        *(float4*)&aL[nl * 64 + f4] = ov;   // safe: phase-A aL reads ended at prior barrier
        __syncthreads();
        if (t < 64) {
            float sm = 0.f, s2 = 0.f;
            #pragma unroll 4
            for (int n = 0; n < 16; n++) {
                float v = aL[n * 64 + t];
                sm += v;
                s2 = fmaf(v, v, s2);
            }
            uadd(bnacc + t, sm);
            uadd(bnacc + 64 + t, s2);
        }
        __syncthreads();
    }
}

// ---------------- BN finalize: scale/shift ----------------
__global__ void k_bnfin(float* bnacc, const float* __restrict__ g, const float* __restrict__ b) {
    int f = threadIdx.x;
    double mu = (double)bnacc[f] / (double)N;
    double var = (double)bnacc[64 + f] / (double)N - mu * mu;
    double inv = 1.0 / sqrt(var + 1e-5);
    double sc = (double)g[f] * inv;
    bnacc[128 + f] = (float)sc;
    bnacc[192 + f] = (float)((double)b[f] - mu * sc);
}

// ---------------- BN apply in place ----------------
__global__ __launch_bounds__(256) void k_bnapply(float* __restrict__ out,
                                                 const float* __restrict__ bnacc) {
    int idx = blockIdx.x * 256 + threadIdx.x;   // float4 index, 800000 total
    int j = idx & 15;
    float4 sc = ((const float4*)(bnacc + 128))[j];
    float4 sh = ((const float4*)(bnacc + 192))[j];
    float4 v = ((float4*)out)[idx];
    v.x = fmaf(v.x, sc.x, sh.x);
    v.y = fmaf(v.y, sc.y, sh.y);
    v.z = fmaf(v.z, sc.z, sh.z);
    v.w = fmaf(v.w, sc.w, sh.w);
    ((float4*)out)[idx] = v;
}

// ---------------- graph mean-pool (stage 1: sums + counts) ----------------
__global__ __launch_bounds__(256) void k_pool(const float* __restrict__ out,
                                              const int* __restrict__ batch,
                                              float* __restrict__ psum,
                                              float* __restrict__ pcnt) {
    int t = threadIdx.x;
    int q = blockIdx.x * 16 + (t >> 4);   // node-quad index
    if (q >= N / 4) return;
    int c = t & 15;
    int n0 = q * 4;
    int gprev = batch[n0];
    float4 acc = {0.f, 0.f, 0.f, 0.f};
    float cnt = 0.f;
    for (int i = 0; i < 4; i++) {
        int n = n0 + i;
        int gb = batch[n];
        float4 v = ((const float4*)(out + (size_t)n * 64))[c];
        if (gb != gprev) {
            float* p = psum + (size_t)gprev * 64 + c * 4;
            uadd(p + 0, acc.x); uadd(p + 1, acc.y); uadd(p + 2, acc.z); uadd(p + 3, acc.w);
            if (c == 0) uadd(pcnt + gprev, cnt);
            acc = make_float4(0.f, 0.f, 0.f, 0.f);
            cnt = 0.f;
            gprev = gb;
        }
        acc.x += v.x; acc.y += v.y; acc.z += v.z; acc.w += v.w;
        cnt += 1.f;
    }
    float* p = psum + (size_t)gprev * 64 + c * 4;
    uadd(p + 0, acc.x); uadd(p + 1, acc.y); uadd(p + 2, acc.z); uadd(p + 3, acc.w);
    if (c == 0) uadd(pcnt + gprev, cnt);
}

// ---------------- head: mean, post FC + relu, out FC ----------------
__global__ __launch_bounds__(256) void k_head(const float* __restrict__ psum,
                                              const float* __restrict__ pcnt,
                                              const float* __restrict__ pW,
                                              const float* __restrict__ pb,
                                              const float* __restrict__ oW,
                                              const float* __restrict__ ob,
                                              float* __restrict__ y) {
    __shared__ float pl[4][64];
    int t = threadIdx.x;
    int gl = t >> 6, f = t & 63;
    int g = blockIdx.x * 4 + gl;
    float cnt = fmaxf(pcnt[g], 1.f);
    pl[gl][f] = psum[(size_t)g * 64 + f] / cnt;
    __syncthreads();
    float acc = pb[f];
    #pragma unroll 4
    for (int j = 0; j < 64; j++) acc = fmaf(pl[gl][j], pW[f * 64 + j], acc);
    float hh = fmaxf(acc, 0.f);
    float part = hh * oW[f];
    #pragma unroll
    for (int off = 32; off; off >>= 1) part += __shfl_xor(part, off);
    if (f == 0) y[g] = part + ob[0];
}

extern "C" void kernel_launch(void* const* d_in, const int* in_sizes, int n_in,
                              void* d_out, int out_size, void* d_ws, size_t ws_size,
                              hipStream_t stream) {
    const float* x      = (const float*)d_in[0];
    const float* ew     = (const float*)d_in[1];
    const float* ea     = (const float*)d_in[2];
    const int*   eidx   = (const int*)d_in[3];
    const int*   batch  = (const int*)d_in[4];
    const float* pre_W  = (const float*)d_in[5];
    const float* pre_b  = (const float*)d_in[6];
    const float* mlp_W1 = (const float*)d_in[7];
    const float* mlp_b1 = (const float*)d_in[8];
    const float* mlp_W2 = (const float*)d_in[9];
    const float* mlp_b2 = (const float*)d_in[10];
    const float* cf_W1  = (const float*)d_in[11];
    const float* cf_W2  = (const float*)d_in[12];
    const float* cf_b2  = (const float*)d_in[13];
    const float* int_W  = (const float*)d_in[14];
    const float* int_b  = (const float*)d_in[15];
    const float* bn_g   = (const float*)d_in[16];
    const float* bn_b   = (const float*)d_in[17];
    const float* post_W = (const float*)d_in[18];
    const float* post_b = (const float*)d_in[19];
    const float* out_W  = (const float*)d_in[20];
    const float* out_b  = (const float*)d_in[21];

    float* ws    = (float*)d_ws;
    float* outb  = ws;                              // N*64
    float* hb    = ws + (size_t)N * 64;             // N*64
    float* aggb  = ws + (size_t)2 * N * 64;         // N*64
    float* bnacc = ws + (size_t)3 * N * 64;         // 256
    float* psum  = bnacc + 256;                     // G*64
    float* pcnt  = psum + (size_t)G * 64;           // G

    k_pre<<<1024, 256, 0, stream>>>(x, pre_W, pre_b, outb);

    for (int l = 0; l < 3; l++) {
        hipMemsetAsync(aggb, 0, (size_t)N * 64 * sizeof(float), stream);
        hipMemsetAsync(bnacc, 0, 128 * sizeof(float), stream);
        k_h<<<1024, 256, 0, stream>>>(outb, cf_W1 + l * 4096, hb);
        k_edge<<<1536, 256, 0, stream>>>(ea, ew, eidx, hb, aggb,
                                         mlp_W1 + l * 3200, mlp_b1 + l * 64,
                                         mlp_W2 + l * 4096, mlp_b2 + l * 64);
        k_post<<<1024, 256, 0, stream>>>(aggb, cf_W2 + l * 4096, cf_b2 + l * 64,
                                         int_W + l * 4096, int_b + l * 64, outb, bnacc);
        k_bnfin<<<1, 64, 0, stream>>>(bnacc, bn_g + l * 64, bn_b + l * 64);
        k_bnapply<<<3125, 256, 0, stream>>>(outb, bnacc);
    }

    hipMemsetAsync(psum, 0, (size_t)(G * 64 + G) * sizeof(float), stream);
    k_pool<<<(N / 4 + 15) / 16, 256, 0, stream>>>(outb, batch, psum, pcnt);
    k_head<<<G / 4, 256, 0, stream>>>(psum, pcnt, post_W, post_b, out_W, out_b, (float*)d_out);
}

// Round 2
// 2524.769 us; speedup vs baseline: 1.5735x; 1.5735x over previous
//
#include <hip/hip_runtime.h>

constexpr int N = 50000;
constexpr int E = 1200000;
constexpr int G = 512;
constexpr int TILES = E / 64;        // 18750 exactly
constexpr float LOG2_ = 0.69314718055994531f;
constexpr float PIC = 0.39269908169872414f;   // pi / 8.0

__device__ __forceinline__ float sspf(float x) {
    // shifted softplus, stable: max(x,0) + log(1+exp(-|x|)) - log(2)
    return fmaxf(x, 0.f) + __logf(1.f + __expf(-fabsf(x))) - LOG2_;
}
__device__ __forceinline__ void uadd(float* p, float v) { unsafeAtomicAdd(p, v); }

// ---------------- sort stage 1: histogram of dst ----------------
__global__ __launch_bounds__(256) void k_hist(const int* __restrict__ eidx,
                                              int* __restrict__ cnt) {
    for (int e = blockIdx.x * 256 + threadIdx.x; e < E; e += gridDim.x * 256)
        atomicAdd(cnt + eidx[E + e], 1);
}

// ---------------- sort stage 2: exclusive scan -> cursor ----------------
__global__ __launch_bounds__(1024) void k_scan(const int* __restrict__ cnt,
                                               int* __restrict__ cursor) {
    __shared__ int part[1024];
    const int CH = 49;                       // 1024*49 = 50176 >= N
    int t = threadIdx.x;
    int b = t * CH;
    int s = 0;
    for (int i = 0; i < CH; i++) { int idx = b + i; if (idx < N) s += cnt[idx]; }
    part[t] = s;
    __syncthreads();
    for (int off = 1; off < 1024; off <<= 1) {
        int add = (t >= off) ? part[t - off] : 0;
        int v = part[t];
        __syncthreads();
        part[t] = v + add;
        __syncthreads();
    }
    int excl = (t == 0) ? 0 : part[t - 1];
    for (int i = 0; i < CH; i++) {
        int idx = b + i;
        if (idx < N) { cursor[idx] = excl; excl += cnt[idx]; }
    }
}

// ---------------- sort stage 3: scatter permutation ----------------
__global__ __launch_bounds__(256) void k_scatter(const int* __restrict__ eidx,
                                                 int* __restrict__ cursor,
                                                 int* __restrict__ order) {
    for (int e = blockIdx.x * 256 + threadIdx.x; e < E; e += gridDim.x * 256) {
        int d = eidx[E + e];
        int p = atomicAdd(cursor + d, 1);
        order[p] = e;
    }
}

// ---------------- pre FC: out = relu(x @ pre_W^T + pre_b) ----------------
__global__ __launch_bounds__(256) void k_pre(const float* __restrict__ x,
                                             const float* __restrict__ W,
                                             const float* __restrict__ b,
                                             float* __restrict__ out) {
    __shared__ float WT[92 * 64];
    __shared__ float xs[4 * 92];
    __shared__ float bs[64];
    for (int i = threadIdx.x; i < 92 * 64; i += 256) {
        int f = i / 92, k = i - f * 92;
        WT[k * 64 + f] = W[i];
    }
    if (threadIdx.x < 64) bs[threadIdx.x] = b[threadIdx.x];
    __syncthreads();
    int f = threadIdx.x & 63, nl = threadIdx.x >> 6;
    for (int g0 = blockIdx.x; g0 < N / 4; g0 += gridDim.x) {
        int n0 = g0 * 4;
        for (int i = threadIdx.x; i < 4 * 92; i += 256) xs[i] = x[(size_t)n0 * 92 + i];
        __syncthreads();
        float acc = bs[f];
        #pragma unroll 4
        for (int k = 0; k < 92; k++) acc = fmaf(xs[nl * 92 + k], WT[k * 64 + f], acc);
        out[(size_t)(n0 + nl) * 64 + f] = fmaxf(acc, 0.f);
        __syncthreads();
    }
}

// ---------------- h = out @ cf_W1^T (no bias) ----------------
__global__ __launch_bounds__(256) void k_h(const float* __restrict__ out,
                                           const float* __restrict__ W,
                                           float* __restrict__ h) {
    __shared__ float WT[64 * 64];
    __shared__ float xs[4 * 64];
    for (int i = threadIdx.x; i < 4096; i += 256) {
        int f = i >> 6, j = i & 63;
        WT[j * 64 + f] = W[i];
    }
    __syncthreads();
    int f = threadIdx.x & 63, nl = threadIdx.x >> 6;
    for (int g0 = blockIdx.x; g0 < N / 4; g0 += gridDim.x) {
        int n0 = g0 * 4;
        if (threadIdx.x < 64)
            ((float4*)xs)[threadIdx.x] = ((const float4*)(out + (size_t)n0 * 64))[threadIdx.x];
        __syncthreads();
        float acc = 0.f;
        #pragma unroll 4
        for (int j = 0; j < 64; j++) acc = fmaf(xs[nl * 64 + j], WT[j * 64 + f], acc);
        h[(size_t)(n0 + nl) * 64 + f] = acc;
        __syncthreads();
    }
}

// ---------------- fused edge kernel (dst-sorted) ----------------
// per 64-edge tile (sorted by dst): t1 = ssp(ea @ W1^T + b1); Wf = t1 @ W2^T + b2;
// Wf *= C; msg = h[src] * Wf; segmented-reduce per dst-run -> store/atomic agg
__global__ __launch_bounds__(256) void k_edge(const float* __restrict__ ea,
                                              const float* __restrict__ ew,
                                              const int* __restrict__ eidx,
                                              const int* __restrict__ order,
                                              const float* __restrict__ h,
                                              float* __restrict__ agg,
                                              const float* __restrict__ W1,
                                              const float* __restrict__ b1,
                                              const float* __restrict__ W2,
                                              const float* __restrict__ b2) {
    constexpr int BS = 68;           // padded row stride (floats) to dodge bank conflicts
    __shared__ float w1T[50 * 64];   // [k][f]
    __shared__ float w2T[64 * 64];   // [j][f]
    __shared__ float buf[64 * BS];   // eaT [k][e] -> tT [j][e] -> msg [e][f]
    __shared__ float b1s[64], b2s[64], c_s[64];
    __shared__ int src_s[64], dst_s[64], ord_s[64];
    int t = threadIdx.x;
    for (int i = t; i < 3200; i += 256) { int f = i / 50, k = i - f * 50; w1T[k * 64 + f] = W1[i]; }
    for (int i = t; i < 4096; i += 256) { int f = i >> 6, j = i & 63; w2T[j * 64 + f] = W2[i]; }
    if (t < 64) { b1s[t] = b1[t]; b2s[t] = b2[t]; }
    __syncthreads();

    const int e4 = (t & 15) * 4;
    const int f4 = (t >> 4) * 4;
    const int fe = t & 63, kq = t >> 6;   // for the transpose gather

    for (int tile = blockIdx.x; tile < TILES; tile += gridDim.x) {
        const int e0 = tile * 64;
        if (t < 64) {
            int e = order[e0 + t];
            ord_s[t] = e;
            src_s[t] = eidx[e];
            dst_s[t] = eidx[E + e];
            c_s[t] = 0.5f * (__cosf(ew[e] * PIC) + 1.0f);
        }
        __syncthreads();
        // --- gather edge_attr rows transposed into buf[k][e] ---
        {
            const float2* row2 = (const float2*)ea + (size_t)ord_s[fe] * 25;
            #pragma unroll
            for (int j = 0; j < 24; j += 4) {
                int kp = j + kq;
                float2 v = row2[kp];
                buf[(2 * kp) * BS + fe] = v.x;
                buf[(2 * kp + 1) * BS + fe] = v.y;
            }
            if (kq == 0) {
                float2 v = row2[24];
                buf[48 * BS + fe] = v.x;
                buf[49 * BS + fe] = v.y;
            }
        }
        __syncthreads();
        // --- GEMM1: a[e][f] = ssp(eaT @ W1 + b1) ---
        float a[4][4];
        #pragma unroll
        for (int i = 0; i < 4; i++)
            #pragma unroll
            for (int j = 0; j < 4; j++) a[i][j] = b1s[f4 + j];
        #pragma unroll 2
        for (int k = 0; k < 50; k++) {
            float4 av = *(const float4*)&buf[k * BS + e4];
            float4 wv = *(const float4*)&w1T[k * 64 + f4];
            float avv[4] = {av.x, av.y, av.z, av.w};
            float wvv[4] = {wv.x, wv.y, wv.z, wv.w};
            #pragma unroll
            for (int i = 0; i < 4; i++)
                #pragma unroll
                for (int j = 0; j < 4; j++) a[i][j] = fmaf(avv[i], wvv[j], a[i][j]);
        }
        #pragma unroll
        for (int i = 0; i < 4; i++)
            #pragma unroll
            for (int j = 0; j < 4; j++) a[i][j] = sspf(a[i][j]);
        __syncthreads();   // eaT reads done
        // --- store tT[j][e] ---
        #pragma unroll
        for (int j = 0; j < 4; j++)
            *(float4*)&buf[(f4 + j) * BS + e4] = make_float4(a[0][j], a[1][j], a[2][j], a[3][j]);
        __syncthreads();
        // --- GEMM2: w[e][f] = tT @ W2 + b2 ---
        float w[4][4];
        #pragma unroll
        for (int i = 0; i < 4; i++)
            #pragma unroll
            for (int j = 0; j < 4; j++) w[i][j] = b2s[f4 + j];
        #pragma unroll 2
        for (int k = 0; k < 64; k++) {
            float4 tv = *(const float4*)&buf[k * BS + e4];
            float4 wv = *(const float4*)&w2T[k * 64 + f4];
            float tvv[4] = {tv.x, tv.y, tv.z, tv.w};
            float wvv[4] = {wv.x, wv.y, wv.z, wv.w};
            #pragma unroll
            for (int i = 0; i < 4; i++)
                #pragma unroll
                for (int j = 0; j < 4; j++) w[i][j] = fmaf(tvv[i], wvv[j], w[i][j]);
        }
        // --- modulate + gather h -> message quad per (edge, f4) ---
        float4 m[4];
        #pragma unroll
        for (int i = 0; i < 4; i++) {
            int eg = e4 + i;
            float Cv = c_s[eg];
            float4 hv = *(const float4*)&h[(size_t)src_s[eg] * 64 + f4];
            m[i] = make_float4(hv.x * w[i][0] * Cv, hv.y * w[i][1] * Cv,
                               hv.z * w[i][2] * Cv, hv.w * w[i][3] * Cv);
        }
        __syncthreads();   // tT reads done before overwrite
        #pragma unroll
        for (int i = 0; i < 4; i++)
            *(float4*)&buf[(e4 + i) * BS + f4] = m[i];
        __syncthreads();
        // --- segmented reduce per dst-run ---
        #pragma unroll
        for (int i = 0; i < 4; i++) {
            int e = e4 + i;
            int d = dst_s[e];
            if (e > 0 && dst_s[e - 1] == d) continue;    // not a run head
            int end = e + 1;
            while (end < 64 && dst_s[end] == d) end++;
            float4 s = *(const float4*)&buf[e * BS + f4];
            for (int r = e + 1; r < end; r++) {
                const float4 v = *(const float4*)&buf[r * BS + f4];
                s.x += v.x; s.y += v.y; s.z += v.z; s.w += v.w;
            }
            float* ap = agg + (size_t)d * 64 + f4;
            if (e > 0 && end < 64) {
                *(float4*)ap = s;                         // run fully inside tile
            } else {
                uadd(ap + 0, s.x); uadd(ap + 1, s.y);
                uadd(ap + 2, s.z); uadd(ap + 3, s.w);
            }
        }
        __syncthreads();   // before next tile overwrites ord_s / dst_s / buf
    }
}

// ---------------- interaction tail + residual + BN stats ----------------
__global__ __launch_bounds__(256) void k_post(const float* __restrict__ agg,
                                              const float* __restrict__ W2c,
                                              const float* __restrict__ b2c,
                                              const float* __restrict__ Wi,
                                              const float* __restrict__ bi,
                                              float* __restrict__ out,
                                              float* __restrict__ bnacc) {
    __shared__ float w2T[64 * 64];
    __shared__ float wiT[64 * 64];
    __shared__ float aL[16 * 64];
    __shared__ float sL[16 * 64];
    __shared__ float b2s[64], bis[64];
    int t = threadIdx.x;
    for (int i = t; i < 4096; i += 256) {
        int f = i >> 6, j = i & 63;
        w2T[j * 64 + f] = W2c[i];
        wiT[j * 64 + f] = Wi[i];
    }
    if (t < 64) { b2s[t] = b2c[t]; bis[t] = bi[t]; }
    __syncthreads();
    const int nl = t >> 4;
    const int f4 = (t & 15) * 4;
    for (int g0 = blockIdx.x; g0 < N / 16; g0 += gridDim.x) {
        int n0 = g0 * 16;
        ((float4*)aL)[t] = ((const float4*)(agg + (size_t)n0 * 64))[t];
        __syncthreads();
        float s[4] = {b2s[f4], b2s[f4 + 1], b2s[f4 + 2], b2s[f4 + 3]};
        #pragma unroll 4
        for (int j = 0; j < 64; j++) {
            float av = aL[nl * 64 + j];
            float4 wv = *(const float4*)&w2T[j * 64 + f4];
            s[0] = fmaf(av, wv.x, s[0]);
            s[1] = fmaf(av, wv.y, s[1]);
            s[2] = fmaf(av, wv.z, s[2]);
            s[3] = fmaf(av, wv.w, s[3]);
        }
        #pragma unroll
        for (int j = 0; j < 4; j++) s[j] = sspf(s[j]);
        *(float4*)&sL[nl * 64 + f4] = make_float4(s[0], s[1], s[2], s[3]);
        __syncthreads();
        float h2[4] = {bis[f4], bis[f4 + 1], bis[f4 + 2], bis[f4 + 3]};
        #pragma unroll 4
        for (int j = 0; j < 64; j++) {
            float sv = sL[nl * 64 + j];
            float4 wv = *(const float4*)&wiT[j * 64 + f4];
            h2[0] = fmaf(sv, wv.x, h2[0]);
            h2[1] = fmaf(sv, wv.y, h2[1]);
            h2[2] = fmaf(sv, wv.z, h2[2]);
            h2[3] = fmaf(sv, wv.w, h2[3]);
        }
        float4 ov = *(const float4*)&out[(size_t)(n0 + nl) * 64 + f4];
        ov.x += h2[0]; ov.y += h2[1]; ov.z += h2[2]; ov.w += h2[3];
        *(float4*)&out[(size_t)(n0 + nl) * 64 + f4] = ov;
        *(float4*)&aL[nl * 64 + f4] = ov;   // safe: phase-A aL reads ended at prior barrier
        __syncthreads();
        if (t < 64) {
            float sm = 0.f, s2 = 0.f;
            #pragma unroll 4
            for (int n = 0; n < 16; n++) {
                float v = aL[n * 64 + t];
                sm += v;
                s2 = fmaf(v, v, s2);
            }
            uadd(bnacc + t, sm);
            uadd(bnacc + 64 + t, s2);
        }
        __syncthreads();
    }
}

// ---------------- BN finalize: scale/shift ----------------
__global__ void k_bnfin(float* bnacc, const float* __restrict__ g, const float* __restrict__ b) {
    int f = threadIdx.x;
    double mu = (double)bnacc[f] / (double)N;
    double var = (double)bnacc[64 + f] / (double)N - mu * mu;
    double inv = 1.0 / sqrt(var + 1e-5);
    double sc = (double)g[f] * inv;
    bnacc[128 + f] = (float)sc;
    bnacc[192 + f] = (float)((double)b[f] - mu * sc);
}

// ---------------- BN apply in place ----------------
__global__ __launch_bounds__(256) void k_bnapply(float* __restrict__ out,
                                                 const float* __restrict__ bnacc) {
    int idx = blockIdx.x * 256 + threadIdx.x;   // float4 index, 800000 total
    int j = idx & 15;
    float4 sc = ((const float4*)(bnacc + 128))[j];
    float4 sh = ((const float4*)(bnacc + 192))[j];
    float4 v = ((float4*)out)[idx];
    v.x = fmaf(v.x, sc.x, sh.x);
    v.y = fmaf(v.y, sc.y, sh.y);
    v.z = fmaf(v.z, sc.z, sh.z);
    v.w = fmaf(v.w, sc.w, sh.w);
    ((float4*)out)[idx] = v;
}

// ---------------- graph mean-pool (stage 1: sums + counts) ----------------
__global__ __launch_bounds__(256) void k_pool(const float* __restrict__ out,
                                              const int* __restrict__ batch,
                                              float* __restrict__ psum,
                                              float* __restrict__ pcnt) {
    int t = threadIdx.x;
    int q = blockIdx.x * 16 + (t >> 4);   // node-quad index
    if (q >= N / 4) return;
    int c = t & 15;
    int n0 = q * 4;
    int gprev = batch[n0];
    float4 acc = {0.f, 0.f, 0.f, 0.f};
    float cnt = 0.f;
    for (int i = 0; i < 4; i++) {
        int n = n0 + i;
        int gb = batch[n];
        float4 v = ((const float4*)(out + (size_t)n * 64))[c];
        if (gb != gprev) {
            float* p = psum + (size_t)gprev * 64 + c * 4;
            uadd(p + 0, acc.x); uadd(p + 1, acc.y); uadd(p + 2, acc.z); uadd(p + 3, acc.w);
            if (c == 0) uadd(pcnt + gprev, cnt);
            acc = make_float4(0.f, 0.f, 0.f, 0.f);
            cnt = 0.f;
            gprev = gb;
        }
        acc.x += v.x; acc.y += v.y; acc.z += v.z; acc.w += v.w;
        cnt += 1.f;
    }
    float* p = psum + (size_t)gprev * 64 + c * 4;
    uadd(p + 0, acc.x); uadd(p + 1, acc.y); uadd(p + 2, acc.z); uadd(p + 3, acc.w);
    if (c == 0) uadd(pcnt + gprev, cnt);
}

// ---------------- head: mean, post FC + relu, out FC ----------------
__global__ __launch_bounds__(256) void k_head(const float* __restrict__ psum,
                                              const float* __restrict__ pcnt,
                                              const float* __restrict__ pW,
                                              const float* __restrict__ pb,
                                              const float* __restrict__ oW,
                                              const float* __restrict__ ob,
                                              float* __restrict__ y) {
    __shared__ float pl[4][64];
    int t = threadIdx.x;
    int gl = t >> 6, f = t & 63;
    int g = blockIdx.x * 4 + gl;
    float cnt = fmaxf(pcnt[g], 1.f);
    pl[gl][f] = psum[(size_t)g * 64 + f] / cnt;
    __syncthreads();
    float acc = pb[f];
    #pragma unroll 4
    for (int j = 0; j < 64; j++) acc = fmaf(pl[gl][j], pW[f * 64 + j], acc);
    float hh = fmaxf(acc, 0.f);
    float part = hh * oW[f];
    #pragma unroll
    for (int off = 32; off; off >>= 1) part += __shfl_xor(part, off);
    if (f == 0) y[g] = part + ob[0];
}

extern "C" void kernel_launch(void* const* d_in, const int* in_sizes, int n_in,
                              void* d_out, int out_size, void* d_ws, size_t ws_size,
                              hipStream_t stream) {
    const float* x      = (const float*)d_in[0];
    const float* ew     = (const float*)d_in[1];
    const float* ea     = (const float*)d_in[2];
    const int*   eidx   = (const int*)d_in[3];
    const int*   batch  = (const int*)d_in[4];
    const float* pre_W  = (const float*)d_in[5];
    const float* pre_b  = (const float*)d_in[6];
    const float* mlp_W1 = (const float*)d_in[7];
    const float* mlp_b1 = (const float*)d_in[8];
    const float* mlp_W2 = (const float*)d_in[9];
    const float* mlp_b2 = (const float*)d_in[10];
    const float* cf_W1  = (const float*)d_in[11];
    const float* cf_W2  = (const float*)d_in[12];
    const float* cf_b2  = (const float*)d_in[13];
    const float* int_W  = (const float*)d_in[14];
    const float* int_b  = (const float*)d_in[15];
    const float* bn_g   = (const float*)d_in[16];
    const float* bn_b   = (const float*)d_in[17];
    const float* post_W = (const float*)d_in[18];
    const float* post_b = (const float*)d_in[19];
    const float* out_W  = (const float*)d_in[20];
    const float* out_b  = (const float*)d_in[21];

    float* ws    = (float*)d_ws;
    float* outb  = ws;                              // N*64
    float* hb    = ws + (size_t)N * 64;             // N*64
    float* aggb  = ws + (size_t)2 * N * 64;         // N*64
    float* bnacc = ws + (size_t)3 * N * 64;         // 256
    float* psum  = bnacc + 256;                     // G*64
    float* pcnt  = psum + (size_t)G * 64;           // G
    int*   cnt   = (int*)(pcnt + G);                // N
    int*   curs  = cnt + N;                         // N
    int*   order = curs + N;                        // E

    // ---- counting sort of edges by dst (once per call) ----
    hipMemsetAsync(cnt, 0, (size_t)N * sizeof(int), stream);
    k_hist<<<1024, 256, 0, stream>>>(eidx, cnt);
    k_scan<<<1, 1024, 0, stream>>>(cnt, curs);
    k_scatter<<<2048, 256, 0, stream>>>(eidx, curs, order);

    k_pre<<<1024, 256, 0, stream>>>(x, pre_W, pre_b, outb);

    for (int l = 0; l < 3; l++) {
        hipMemsetAsync(aggb, 0, (size_t)N * 64 * sizeof(float), stream);
        hipMemsetAsync(bnacc, 0, 128 * sizeof(float), stream);
        k_h<<<1024, 256, 0, stream>>>(outb, cf_W1 + l * 4096, hb);
        k_edge<<<1536, 256, 0, stream>>>(ea, ew, eidx, order, hb, aggb,
                                         mlp_W1 + l * 3200, mlp_b1 + l * 64,
                                         mlp_W2 + l * 4096, mlp_b2 + l * 64);
        k_post<<<1024, 256, 0, stream>>>(aggb, cf_W2 + l * 4096, cf_b2 + l * 64,
                                         int_W + l * 4096, int_b + l * 64, outb, bnacc);
        k_bnfin<<<1, 64, 0, stream>>>(bnacc, bn_g + l * 64, bn_b + l * 64);
        k_bnapply<<<3125, 256, 0, stream>>>(outb, bnacc);
    }

    hipMemsetAsync(psum, 0, (size_t)(G * 64 + G) * sizeof(float), stream);
    k_pool<<<(N / 4 + 15) / 16, 256, 0, stream>>>(outb, batch, psum, pcnt);
    k_head<<<G / 4, 256, 0, stream>>>(psum, pcnt, post_W, post_b, out_W, out_b, (float*)d_out);
}